// Round 3
// baseline (7101.511 us; speedup 1.0000x reference)
//
#include <hip/hip_runtime.h>

#define BN_EPS 1e-5f

typedef unsigned short u16;

__device__ __forceinline__ float bf2f(u16 u) {
    return __uint_as_float(((unsigned)u) << 16);
}
__device__ __forceinline__ u16 f2bf(float f) {
    unsigned u = __float_as_uint(f);
    u += 0x7FFFu + ((u >> 16) & 1u);
    return (u16)(u >> 16);
}

// ---------------------------------------------------------------------------
// counts: cr[n*3+t] (SCRE, aggregated at row), cc[n*3+t] (RGCN, at col)
__global__ __launch_bounds__(256) void k_count(const int* __restrict__ ei,
                                               const int* __restrict__ et,
                                               float* __restrict__ cr,
                                               float* __restrict__ cc, int E) {
    int e = blockIdx.x * 256 + threadIdx.x;
    if (e >= E) return;
    int r = ei[e], c = ei[E + e], t = et[e];
    atomicAdd(cr + (size_t)r * 3 + t, 1.0f);
    atomicAdd(cc + (size_t)c * 3 + t, 1.0f);
}

// cr[n,t] := cnt>0 ? 1/(cnt*relcount(n)) : 0 ; cc[n,t] := cnt>0 ? 1/cnt : 0
__global__ __launch_bounds__(256) void k_scales(float* __restrict__ cr,
                                                float* __restrict__ cc, int N) {
    int n = blockIdx.x * 256 + threadIdx.x;
    if (n >= N) return;
    float c0 = cr[n * 3 + 0], c1 = cr[n * 3 + 1], c2 = cr[n * 3 + 2];
    float relc = (c0 > 0.f ? 1.f : 0.f) + (c1 > 0.f ? 1.f : 0.f) + (c2 > 0.f ? 1.f : 0.f);
    if (relc < 1.f) relc = 1.f;
    cr[n * 3 + 0] = c0 > 0.f ? 1.f / (c0 * relc) : 0.f;
    cr[n * 3 + 1] = c1 > 0.f ? 1.f / (c1 * relc) : 0.f;
    cr[n * 3 + 2] = c2 > 0.f ? 1.f / (c2 * relc) : 0.f;
    float d0 = cc[n * 3 + 0], d1 = cc[n * 3 + 1], d2 = cc[n * 3 + 2];
    cc[n * 3 + 0] = d0 > 0.f ? 1.f / d0 : 0.f;
    cc[n * 3 + 1] = d1 > 0.f ? 1.f / d1 : 0.f;
    cc[n * 3 + 2] = d2 > 0.f ? 1.f / d2 : 0.f;
}

// SCRE: acc[r-n0] += x[c] * scale[r,t]   for r in [n0,n1)
__global__ __launch_bounds__(256) void k_scre_agg(const float* __restrict__ x,
                                                  const int* __restrict__ ei,
                                                  const int* __restrict__ et,
                                                  const float* __restrict__ scale,
                                                  float* __restrict__ acc,
                                                  int E, int n0, int n1) {
    int idx = blockIdx.x * 256 + threadIdx.x;
    int e = idx >> 6;
    if (e >= E) return;
    int r = ei[e];
    if (r < n0 || r >= n1) return;
    int lane = idx & 63;
    int c = ei[E + e], t = et[e];
    float s = scale[(size_t)r * 3 + t];
    const float4 v = *reinterpret_cast<const float4*>(x + (size_t)c * 256 + lane * 4);
    float* dst = acc + (size_t)(r - n0) * 256 + lane * 4;
    atomicAdd(dst + 0, v.x * s);
    atomicAdd(dst + 1, v.y * s);
    atomicAdd(dst + 2, v.z * s);
    atomicAdd(dst + 3, v.w * s);
}

// h[n0+lr] = bf16(x[n0+lr] - acc[lr])
__global__ __launch_bounds__(256) void k_sub_chunk(const float* __restrict__ x,
                                                   const float* __restrict__ acc,
                                                   u16* __restrict__ h,
                                                   int n0, int Mc) {
    int idx = blockIdx.x * 256 + threadIdx.x;
    int lr = idx >> 6;
    if (lr >= Mc) return;
    int lane = idx & 63;
    size_t g = (size_t)(n0 + lr) * 256 + lane * 4;
    float4 a = *reinterpret_cast<const float4*>(x + g);
    float4 b = *reinterpret_cast<const float4*>(acc + (size_t)lr * 256 + lane * 4);
    ushort4 o;
    o.x = f2bf(a.x - b.x);
    o.y = f2bf(a.y - b.y);
    o.z = f2bf(a.z - b.z);
    o.w = f2bf(a.w - b.w);
    *reinterpret_cast<ushort4*>(h + g) = o;
}

// RGCN mean agg: sums[((c-n0)*3+t)] += src[r] * invc[c,t]   for c in [n0,n1)
__global__ __launch_bounds__(256) void k_rgcn_agg(const u16* __restrict__ src,
                                                  const int* __restrict__ ei,
                                                  const int* __restrict__ et,
                                                  const float* __restrict__ invc,
                                                  float* __restrict__ sums,
                                                  int E, int n0, int n1) {
    int idx = blockIdx.x * 256 + threadIdx.x;
    int e = idx >> 6;
    if (e >= E) return;
    int c = ei[E + e];
    if (c < n0 || c >= n1) return;
    int lane = idx & 63;
    int r = ei[e], t = et[e];
    float s = invc[(size_t)c * 3 + t];
    ushort4 v = *reinterpret_cast<const ushort4*>(src + (size_t)r * 256 + lane * 4);
    float* dst = sums + ((size_t)(c - n0) * 3 + t) * 256 + lane * 4;
    atomicAdd(dst + 0, bf2f(v.x) * s);
    atomicAdd(dst + 1, bf2f(v.y) * s);
    atomicAdd(dst + 2, bf2f(v.z) * s);
    atomicAdd(dst + 3, bf2f(v.w) * s);
}

// Fused GEMM: out = bf16( relu(BN( A1@W1 + A2@W2 + bias )) )
// A1 fp32 (lda=K1), A2 bf16 (lda=K2); W* fp32 (K,256); out width 256.
// 64x64 tile, 256 threads, 4x4 per thread, fp32 accum.
__global__ __launch_bounds__(256) void k_gemm_bn_relu(
    const float* __restrict__ A1, int K1, const float* __restrict__ W1,
    const u16* __restrict__ A2, int K2, const float* __restrict__ W2,
    const float* __restrict__ bias,
    const float* __restrict__ bng, const float* __restrict__ bnb,
    const float* __restrict__ bnm, const float* __restrict__ bnv,
    u16* __restrict__ out, int M) {
    __shared__ float As[16][68];
    __shared__ float Bs[16][68];
    const int tid = threadIdx.x;
    const int ty = tid >> 4, tx = tid & 15;
    const int m0 = blockIdx.x * 64;
    const int n0 = blockIdx.y * 64;

    float acc[4][4] = {};

    const int lrow = tid >> 2;        // A: row in tile 0..63
    const int lkc = (tid & 3) * 4;    // A: k offset 0,4,8,12
    const int bk = tid >> 4;          // B: k row 0..15
    const int bc = (tid & 15) * 4;    // B: col 0..60

    for (int pass = 0; pass < 2; ++pass) {
        const int K = pass ? K2 : K1;
        if (K == 0) continue;
        const float* W = pass ? W2 : W1;
        const int gm = m0 + lrow;
        const bool arow_ok = gm < M;
        for (int k0 = 0; k0 < K; k0 += 16) {
            float4 av = make_float4(0.f, 0.f, 0.f, 0.f);
            if (arow_ok) {
                if (pass == 0) {
                    av = *reinterpret_cast<const float4*>(A1 + (size_t)gm * K1 + k0 + lkc);
                } else {
                    ushort4 t4 = *reinterpret_cast<const ushort4*>(A2 + (size_t)gm * K2 + k0 + lkc);
                    av = make_float4(bf2f(t4.x), bf2f(t4.y), bf2f(t4.z), bf2f(t4.w));
                }
            }
            float4 bv = *reinterpret_cast<const float4*>(W + (size_t)(k0 + bk) * 256 + n0 + bc);
            __syncthreads();
            As[lkc + 0][lrow] = av.x;
            As[lkc + 1][lrow] = av.y;
            As[lkc + 2][lrow] = av.z;
            As[lkc + 3][lrow] = av.w;
            *reinterpret_cast<float4*>(&Bs[bk][bc]) = bv;
            __syncthreads();
#pragma unroll
            for (int kk = 0; kk < 16; ++kk) {
                float4 a4 = *reinterpret_cast<const float4*>(&As[kk][ty * 4]);
                float4 b4 = *reinterpret_cast<const float4*>(&Bs[kk][tx * 4]);
                float a[4] = {a4.x, a4.y, a4.z, a4.w};
                float b[4] = {b4.x, b4.y, b4.z, b4.w};
#pragma unroll
                for (int i = 0; i < 4; ++i)
#pragma unroll
                    for (int j = 0; j < 4; ++j) acc[i][j] += a[i] * b[j];
            }
        }
    }

    float ga[4], be[4];
#pragma unroll
    for (int j = 0; j < 4; ++j) {
        int o = n0 + tx * 4 + j;
        float g = bng[o];
        ga[j] = g * rsqrtf(bnv[o] + BN_EPS);
        be[j] = bnb[o] + (bias[o] - bnm[o]) * ga[j];
    }
#pragma unroll
    for (int i = 0; i < 4; ++i) {
        int row = m0 + ty * 4 + i;
        if (row >= M) continue;
        float y0 = acc[i][0] * ga[0] + be[0];
        float y1 = acc[i][1] * ga[1] + be[1];
        float y2 = acc[i][2] * ga[2] + be[2];
        float y3 = acc[i][3] * ga[3] + be[3];
        ushort4 st;
        st.x = f2bf(y0 > 0.f ? y0 : 0.f);
        st.y = f2bf(y1 > 0.f ? y1 : 0.f);
        st.z = f2bf(y2 > 0.f ? y2 : 0.f);
        st.w = f2bf(y3 > 0.f ? y3 : 0.f);
        *reinterpret_cast<ushort4*>(out + (size_t)row * 256 + n0 + tx * 4) = st;
    }
}

// head: out[n] = dot(zm[n], ow[0:256]) + dot(zg[n], ow[256:512]) + ob
__global__ __launch_bounds__(256) void k_head(const u16* __restrict__ zm,
                                              const u16* __restrict__ zg,
                                              const float* __restrict__ ow,
                                              const float* __restrict__ ob,
                                              float* __restrict__ out, int N) {
    int n = blockIdx.x * 4 + (threadIdx.x >> 6);
    if (n >= N) return;
    int lane = threadIdx.x & 63;
    ushort4 a = *reinterpret_cast<const ushort4*>(zm + (size_t)n * 256 + lane * 4);
    float4 w = *reinterpret_cast<const float4*>(ow + lane * 4);
    float s = bf2f(a.x) * w.x + bf2f(a.y) * w.y + bf2f(a.z) * w.z + bf2f(a.w) * w.w;
    ushort4 b = *reinterpret_cast<const ushort4*>(zg + (size_t)n * 256 + lane * 4);
    float4 w2 = *reinterpret_cast<const float4*>(ow + 256 + lane * 4);
    s += bf2f(b.x) * w2.x + bf2f(b.y) * w2.y + bf2f(b.z) * w2.z + bf2f(b.w) * w2.w;
#pragma unroll
    for (int off = 32; off > 0; off >>= 1) s += __shfl_down(s, off);
    if (lane == 0) out[n] = s + ob[0];
}

extern "C" void kernel_launch(void* const* d_in, const int* in_sizes, int n_in,
                              void* d_out, int out_size, void* d_ws, size_t ws_size,
                              hipStream_t stream) {
    const float* x = (const float*)d_in[0];
    const int* ei = (const int*)d_in[1];
    const int* et = (const int*)d_in[2];
    const float* mlp_w1 = (const float*)d_in[3];
    const float* mlp_b1 = (const float*)d_in[4];
    const float* mbn1_g = (const float*)d_in[5];
    const float* mbn1_b = (const float*)d_in[6];
    const float* mbn1_m = (const float*)d_in[7];
    const float* mbn1_v = (const float*)d_in[8];
    const float* mlp_w2 = (const float*)d_in[9];
    const float* mlp_b2 = (const float*)d_in[10];
    const float* mbn2_g = (const float*)d_in[11];
    const float* mbn2_b = (const float*)d_in[12];
    const float* mbn2_m = (const float*)d_in[13];
    const float* mbn2_v = (const float*)d_in[14];
    const float* r1_wrel = (const float*)d_in[15];
    const float* r1_wroot = (const float*)d_in[16];
    const float* r1_b = (const float*)d_in[17];
    const float* gbn1_g = (const float*)d_in[18];
    const float* gbn1_b = (const float*)d_in[19];
    const float* gbn1_m = (const float*)d_in[20];
    const float* gbn1_v = (const float*)d_in[21];
    const float* r2_wrel = (const float*)d_in[22];
    const float* r2_wroot = (const float*)d_in[23];
    const float* r2_b = (const float*)d_in[24];
    const float* gbn2_g = (const float*)d_in[25];
    const float* gbn2_b = (const float*)d_in[26];
    const float* gbn2_m = (const float*)d_in[27];
    const float* gbn2_v = (const float*)d_in[28];
    const float* out_w = (const float*)d_in[29];
    const float* out_b = (const float*)d_in[30];

    const int N = in_sizes[0] / 256;
    const int E = in_sizes[2];

    // ---- workspace layout (adaptive) ----
    // fixed: scales (N*6 f32) + 3 bf16 feature regions (N*256 u16 each)
    // chunk: fp32 accum buffer, Nc*768 f32 (also used as Nc*256 for SCRE)
    size_t fixedB = (size_t)N * 6 * 4 + 3 * (size_t)N * 256 * 2;
    size_t avail = (ws_size > fixedB) ? ws_size - fixedB : 0;
    size_t ncap = avail / ((size_t)768 * 4);
    if (ncap < 2048) {
        // workspace too small: emit clean wrong-answer instead of faulting
        hipMemsetAsync(d_out, 0, (size_t)out_size * 4, stream);
        return;
    }
    int Nc = (int)((ncap < (size_t)N) ? ncap : (size_t)N);
    int nch = (N + Nc - 1) / Nc;
    Nc = (N + nch - 1) / nch;  // rebalance

    float* sc_r = (float*)d_ws;                       // N*3
    float* sc_c = sc_r + (size_t)N * 3;               // N*3
    u16* regA = (u16*)(sc_c + (size_t)N * 3);         // N*256 bf16: z1_mlp -> h -> z_gnn
    u16* regB = regA + (size_t)N * 256;               // N*256 bf16: z_mlp
    u16* regC = regB + (size_t)N * 256;               // N*256 bf16: z1_gnn
    float* CH = (float*)(regC + (size_t)N * 256);     // Nc*768 f32 chunk accum

    const int agg_blocks = (E * 64 + 255) / 256;

    // counts + scales
    hipMemsetAsync(sc_r, 0, (size_t)N * 6 * 4, stream);
    k_count<<<(E + 255) / 256, 256, 0, stream>>>(ei, et, sc_r, sc_c, E);
    k_scales<<<(N + 255) / 256, 256, 0, stream>>>(sc_r, sc_c, N);

    // MLP branch: regA = relu(bn1(x@w1+b1)); regB = relu(bn2(regA@w2+b2))
    {
        dim3 g((N + 63) / 64, 4);
        k_gemm_bn_relu<<<g, 256, 0, stream>>>(x, 256, mlp_w1, nullptr, 0, nullptr,
                                              mlp_b1, mbn1_g, mbn1_b, mbn1_m, mbn1_v,
                                              regA, N);
        k_gemm_bn_relu<<<g, 256, 0, stream>>>(nullptr, 0, nullptr, regA, 256, mlp_w2,
                                              mlp_b2, mbn2_g, mbn2_b, mbn2_m, mbn2_v,
                                              regB, N);
    }

    // SCRE: regA := bf16(h) = x - folded neighbor-mean (chunked)
    for (int ch = 0; ch < nch; ++ch) {
        int n0 = ch * Nc;
        int n1 = (n0 + Nc < N) ? n0 + Nc : N;
        int Mc = n1 - n0;
        hipMemsetAsync(CH, 0, (size_t)Mc * 256 * 4, stream);
        k_scre_agg<<<agg_blocks, 256, 0, stream>>>(x, ei, et, sc_r, CH, E, n0, n1);
        k_sub_chunk<<<(Mc * 64 + 255) / 256, 256, 0, stream>>>(x, CH, regA, n0, Mc);
    }

    // RGCN layer 1: regC = relu(bn(means(h)@wrel + h@wroot + b)) (chunked)
    for (int ch = 0; ch < nch; ++ch) {
        int n0 = ch * Nc;
        int n1 = (n0 + Nc < N) ? n0 + Nc : N;
        int Mc = n1 - n0;
        hipMemsetAsync(CH, 0, (size_t)Mc * 768 * 4, stream);
        k_rgcn_agg<<<agg_blocks, 256, 0, stream>>>(regA, ei, et, sc_c, CH, E, n0, n1);
        dim3 g((Mc + 63) / 64, 4);
        k_gemm_bn_relu<<<g, 256, 0, stream>>>(CH, 768, r1_wrel,
                                              regA + (size_t)n0 * 256, 256, r1_wroot,
                                              r1_b, gbn1_g, gbn1_b, gbn1_m, gbn1_v,
                                              regC + (size_t)n0 * 256, Mc);
    }

    // RGCN layer 2: regA = z_gnn = relu(bn(means(z1)@wrel + z1@wroot + b)) (chunked)
    for (int ch = 0; ch < nch; ++ch) {
        int n0 = ch * Nc;
        int n1 = (n0 + Nc < N) ? n0 + Nc : N;
        int Mc = n1 - n0;
        hipMemsetAsync(CH, 0, (size_t)Mc * 768 * 4, stream);
        k_rgcn_agg<<<agg_blocks, 256, 0, stream>>>(regC, ei, et, sc_c, CH, E, n0, n1);
        dim3 g((Mc + 63) / 64, 4);
        k_gemm_bn_relu<<<g, 256, 0, stream>>>(CH, 768, r2_wrel,
                                              regC + (size_t)n0 * 256, 256, r2_wroot,
                                              r2_b, gbn2_g, gbn2_b, gbn2_m, gbn2_v,
                                              regA + (size_t)n0 * 256, Mc);
    }

    // head
    k_head<<<(N + 3) / 4, 256, 0, stream>>>(regB, regA, out_w, out_b, (float*)d_out, N);
}

// Round 5
// 1037.503 us; speedup vs baseline: 6.8448x; 6.8448x over previous
//
#include <hip/hip_runtime.h>

#define BN_EPS 1e-5f

typedef unsigned short u16;
typedef short bf16x8 __attribute__((ext_vector_type(8)));
typedef float f32x4 __attribute__((ext_vector_type(4)));

__device__ __forceinline__ float bf2f(u16 u) {
    return __uint_as_float(((unsigned)u) << 16);
}
__device__ __forceinline__ u16 f2bf(float f) {
    unsigned u = __float_as_uint(f);
    u += 0x7FFFu + ((u >> 16) & 1u);
    return (u16)(u >> 16);
}

// ---------------------------------------------------------------------------
// counts: cntR[r] (edges per row), cntRT[r*3+t], cntCT[c*3+t]
__global__ __launch_bounds__(256) void k_count(const int* __restrict__ ei,
                                               const int* __restrict__ et,
                                               int* __restrict__ cntR,
                                               int* __restrict__ cntRT,
                                               int* __restrict__ cntCT, int E) {
    int e = blockIdx.x * 256 + threadIdx.x;
    if (e >= E) return;
    int r = ei[e], c = ei[E + e], t = et[e];
    atomicAdd(cntR + r, 1);
    atomicAdd(cntRT + (size_t)r * 3 + t, 1);
    atomicAdd(cntCT + (size_t)c * 3 + t, 1);
}

// SCRE folded coefficient: sc_r[n,t] = cnt>0 ? 1/(cnt*relcount(n)) : 0
__global__ __launch_bounds__(256) void k_scales(const int* __restrict__ cntRT,
                                                float* __restrict__ sc_r, int N) {
    int n = blockIdx.x * 256 + threadIdx.x;
    if (n >= N) return;
    int c0 = cntRT[n * 3 + 0], c1 = cntRT[n * 3 + 1], c2 = cntRT[n * 3 + 2];
    float relc = (float)((c0 > 0) + (c1 > 0) + (c2 > 0));
    if (relc < 1.f) relc = 1.f;
    sc_r[n * 3 + 0] = c0 > 0 ? 1.f / ((float)c0 * relc) : 0.f;
    sc_r[n * 3 + 1] = c1 > 0 ? 1.f / ((float)c1 * relc) : 0.f;
    sc_r[n * 3 + 2] = c2 > 0 ? 1.f / ((float)c2 * relc) : 0.f;
}

// ---- exclusive scan (3 kernels); n <= 256*2048 ----
__global__ __launch_bounds__(256) void k_scan1(const int* __restrict__ in,
                                               int* __restrict__ out,
                                               int* __restrict__ bsums, int n) {
    __shared__ int sh[256];
    int t = threadIdx.x, base = blockIdx.x * 2048 + t * 8;
    int v[8];
    int s = 0;
#pragma unroll
    for (int j = 0; j < 8; ++j) {
        int idx = base + j;
        v[j] = idx < n ? in[idx] : 0;
        s += v[j];
    }
    sh[t] = s;
    __syncthreads();
    for (int off = 1; off < 256; off <<= 1) {
        int val = (t >= off) ? sh[t - off] : 0;
        __syncthreads();
        sh[t] += val;
        __syncthreads();
    }
    int run = sh[t] - s;  // exclusive thread base
    if (t == 255) bsums[blockIdx.x] = sh[255];
#pragma unroll
    for (int j = 0; j < 8; ++j) {
        int idx = base + j;
        if (idx < n) out[idx] = run;
        run += v[j];
    }
}
__global__ __launch_bounds__(256) void k_scan2(int* __restrict__ bsums, int nb) {
    __shared__ int sh[256];
    int t = threadIdx.x;
    int v = t < nb ? bsums[t] : 0;
    sh[t] = v;
    __syncthreads();
    for (int off = 1; off < 256; off <<= 1) {
        int val = (t >= off) ? sh[t - off] : 0;
        __syncthreads();
        sh[t] += val;
        __syncthreads();
    }
    if (t < nb) bsums[t] = sh[t] - v;
}
__global__ __launch_bounds__(256) void k_scan3(int* __restrict__ out,
                                               const int* __restrict__ bsums, int n) {
    int i = blockIdx.x * 2048 + threadIdx.x * 8;
    int add = bsums[blockIdx.x];
#pragma unroll
    for (int j = 0; j < 8; ++j)
        if (i + j < n) out[i + j] += add;
}

// scatter edges into both CSRs
__global__ __launch_bounds__(256) void k_scatter(const int* __restrict__ ei,
                                                 const int* __restrict__ et,
                                                 const float* __restrict__ sc_r,
                                                 const int* __restrict__ offR,
                                                 int* __restrict__ fillR,
                                                 int* __restrict__ idxR,
                                                 float* __restrict__ coefR,
                                                 const int* __restrict__ offC,
                                                 int* __restrict__ fillC,
                                                 int* __restrict__ idxC, int E) {
    int e = blockIdx.x * 256 + threadIdx.x;
    if (e >= E) return;
    int r = ei[e], c = ei[E + e], t = et[e];
    int pR = offR[r] + atomicAdd(fillR + r, 1);
    idxR[pR] = c;
    coefR[pR] = sc_r[(size_t)r * 3 + t];
    int key = c * 3 + t;
    int pC = offC[key] + atomicAdd(fillC + key, 1);
    idxC[pC] = r;
}

// SCRE gather: one wave per node; h[n] = bf16(x[n] - sum coef*x[col])
__global__ __launch_bounds__(256) void k_scre_gather(const float* __restrict__ x,
                                                     const int* __restrict__ idxR,
                                                     const float* __restrict__ coefR,
                                                     const int* __restrict__ offR,
                                                     const int* __restrict__ cntR,
                                                     u16* __restrict__ h, int N) {
    int node = blockIdx.x * 4 + (threadIdx.x >> 6);
    if (node >= N) return;
    int lane = threadIdx.x & 63;
    int start = offR[node], len = cntR[node];
    float4 acc = make_float4(0.f, 0.f, 0.f, 0.f);
    for (int i = 0; i < len; ++i) {
        int c = idxR[start + i];
        float s = coefR[start + i];
        float4 v = *reinterpret_cast<const float4*>(x + (size_t)c * 256 + lane * 4);
        acc.x += s * v.x;
        acc.y += s * v.y;
        acc.z += s * v.z;
        acc.w += s * v.w;
    }
    float4 xv = *reinterpret_cast<const float4*>(x + (size_t)node * 256 + lane * 4);
    ushort4 o;
    o.x = f2bf(xv.x - acc.x);
    o.y = f2bf(xv.y - acc.y);
    o.z = f2bf(xv.z - acc.z);
    o.w = f2bf(xv.w - acc.w);
    *reinterpret_cast<ushort4*>(h + (size_t)node * 256 + lane * 4) = o;
}

// RGCN gather: one wave per (node,rel) segment in [s0,s1); means bf16 at (seg-s0)*256
__global__ __launch_bounds__(256) void k_rgcn_gather(const u16* __restrict__ src,
                                                     const int* __restrict__ idxC,
                                                     const int* __restrict__ offC,
                                                     const int* __restrict__ cntC,
                                                     u16* __restrict__ means,
                                                     int s0, int s1) {
    int seg = s0 + blockIdx.x * 4 + (threadIdx.x >> 6);
    if (seg >= s1) return;
    int lane = threadIdx.x & 63;
    int start = offC[seg], len = cntC[seg];
    float4 acc = make_float4(0.f, 0.f, 0.f, 0.f);
    for (int i = 0; i < len; ++i) {
        int r = idxC[start + i];
        ushort4 v = *reinterpret_cast<const ushort4*>(src + (size_t)r * 256 + lane * 4);
        acc.x += bf2f(v.x);
        acc.y += bf2f(v.y);
        acc.z += bf2f(v.z);
        acc.w += bf2f(v.w);
    }
    float inv = len > 0 ? 1.f / (float)len : 0.f;
    ushort4 o;
    o.x = f2bf(acc.x * inv);
    o.y = f2bf(acc.y * inv);
    o.z = f2bf(acc.z * inv);
    o.w = f2bf(acc.w * inv);
    *reinterpret_cast<ushort4*>(means + (size_t)(seg - s0) * 256 + lane * 4) = o;
}

// weight transpose+convert: W[K][256] fp32 -> Wt[256][K] bf16 (32x32 LDS tiles)
__global__ __launch_bounds__(256) void k_wt(const float* __restrict__ W,
                                            u16* __restrict__ Wt, int K) {
    __shared__ float tile[32][33];
    int kb = blockIdx.x * 32, nb = blockIdx.y * 32;
    int tx = threadIdx.x & 31, ty = threadIdx.x >> 5;  // 8 rows per pass
#pragma unroll
    for (int j = 0; j < 4; ++j) {
        int k = kb + ty + j * 8;
        tile[ty + j * 8][tx] = W[(size_t)k * 256 + nb + tx];
    }
    __syncthreads();
#pragma unroll
    for (int j = 0; j < 4; ++j) {
        int n = nb + ty + j * 8;
        Wt[(size_t)n * K + kb + tx] = f2bf(tile[tx][ty + j * 8]);
    }
}

// ---------------------------------------------------------------------------
// MFMA GEMM: out = bf16(relu(BN( A1@W1t^T + A2@W2t^T + bias )))
// A: [M][K] (bf16, or fp32 if A1_F32 for pass 1). Wt: [256][K] bf16.
// 128x128 tile, 256 threads = 4 waves (2x2), each wave 64x64 via 4x4 frags
// of v_mfma_f32_16x16x32_bf16. LDS K-stride padded to 40 bf16 (80B).
#define LDK 40

template <int A1_F32>
__global__ __launch_bounds__(256) void k_gemm_mfma(
    const void* __restrict__ A1v, int K1, const u16* __restrict__ W1t,
    const u16* __restrict__ A2, int K2, const u16* __restrict__ W2t,
    const float* __restrict__ bias,
    const float* __restrict__ bng, const float* __restrict__ bnb,
    const float* __restrict__ bnm, const float* __restrict__ bnv,
    u16* __restrict__ out, int M) {
    __shared__ u16 Asm[128 * LDK];
    __shared__ u16 Bsm[128 * LDK];
    const int tid = threadIdx.x;
    const int lane = tid & 63;
    const int wid = tid >> 6;
    const int wr = wid >> 1, wc = wid & 1;
    const int m0 = blockIdx.x * 128, n0 = blockIdx.y * 128;
    const int frow = lane & 15, fk = (lane >> 4) * 8;

    f32x4 acc[4][4] = {};

    for (int pass = 0; pass < 2; ++pass) {
        const int K = pass ? K2 : K1;
        if (K == 0) continue;
        const u16* Wt = pass ? W2t : W1t;
        for (int k0 = 0; k0 < K; k0 += 32) {
            __syncthreads();
#pragma unroll
            for (int j = 0; j < 2; ++j) {
                int q = tid + 256 * j;
                int row = q >> 2, kc = (q & 3) * 8;
                int gm = m0 + row;
                bf16x8 av = {};
                if (gm < M) {
                    if (pass == 0 && A1_F32) {
                        const float* p = (const float*)A1v + (size_t)gm * K + k0 + kc;
#pragma unroll
                        for (int e2 = 0; e2 < 8; ++e2)
                            ((u16*)&av)[e2] = f2bf(p[e2]);
                    } else {
                        const u16* Ab = pass ? A2 : (const u16*)A1v;
                        av = *reinterpret_cast<const bf16x8*>(Ab + (size_t)gm * K + k0 + kc);
                    }
                }
                *reinterpret_cast<bf16x8*>(&Asm[row * LDK + kc]) = av;
                bf16x8 wv = *reinterpret_cast<const bf16x8*>(Wt + (size_t)(n0 + row) * K + k0 + kc);
                *reinterpret_cast<bf16x8*>(&Bsm[row * LDK + kc]) = wv;
            }
            __syncthreads();
            bf16x8 af[4], bf[4];
#pragma unroll
            for (int i = 0; i < 4; ++i) {
                af[i] = *reinterpret_cast<const bf16x8*>(&Asm[(wr * 64 + i * 16 + frow) * LDK + fk]);
                bf[i] = *reinterpret_cast<const bf16x8*>(&Bsm[(wc * 64 + i * 16 + frow) * LDK + fk]);
            }
#pragma unroll
            for (int i = 0; i < 4; ++i)
#pragma unroll
                for (int j2 = 0; j2 < 4; ++j2)
                    acc[i][j2] = __builtin_amdgcn_mfma_f32_16x16x32_bf16(af[i], bf[j2], acc[i][j2], 0, 0, 0);
        }
    }

    // epilogue: C/D frag layout col=lane&15, row=(lane>>4)*4+j [m89-verified]
    const int crow = (lane >> 4) * 4;
#pragma unroll
    for (int fj = 0; fj < 4; ++fj) {
        int col = n0 + wc * 64 + fj * 16 + frow;
        float g = bng[col] * rsqrtf(bnv[col] + BN_EPS);
        float be = bnb[col] + (bias[col] - bnm[col]) * g;
#pragma unroll
        for (int fi = 0; fi < 4; ++fi) {
#pragma unroll
            for (int j = 0; j < 4; ++j) {
                int row = m0 + wr * 64 + fi * 16 + crow + j;
                if (row < M) {
                    float y = acc[fi][fj][j] * g + be;
                    out[(size_t)row * 256 + col] = f2bf(y > 0.f ? y : 0.f);
                }
            }
        }
    }
}

// head: out[n] = dot(zm[n], ow[0:256]) + dot(zg[n], ow[256:512]) + ob
__global__ __launch_bounds__(256) void k_head(const u16* __restrict__ zm,
                                              const u16* __restrict__ zg,
                                              const float* __restrict__ ow,
                                              const float* __restrict__ ob,
                                              float* __restrict__ out, int N) {
    int n = blockIdx.x * 4 + (threadIdx.x >> 6);
    if (n >= N) return;
    int lane = threadIdx.x & 63;
    ushort4 a = *reinterpret_cast<const ushort4*>(zm + (size_t)n * 256 + lane * 4);
    float4 w = *reinterpret_cast<const float4*>(ow + lane * 4);
    float s = bf2f(a.x) * w.x + bf2f(a.y) * w.y + bf2f(a.z) * w.z + bf2f(a.w) * w.w;
    ushort4 b = *reinterpret_cast<const ushort4*>(zg + (size_t)n * 256 + lane * 4);
    float4 w2 = *reinterpret_cast<const float4*>(ow + 256 + lane * 4);
    s += bf2f(b.x) * w2.x + bf2f(b.y) * w2.y + bf2f(b.z) * w2.z + bf2f(b.w) * w2.w;
#pragma unroll
    for (int off = 32; off > 0; off >>= 1) s += __shfl_down(s, off);
    if (lane == 0) out[n] = s + ob[0];
}

// ---------------------------------------------------------------------------
static inline size_t alignup(size_t x) { return (x + 255) & ~(size_t)255; }

extern "C" void kernel_launch(void* const* d_in, const int* in_sizes, int n_in,
                              void* d_out, int out_size, void* d_ws, size_t ws_size,
                              hipStream_t stream) {
    const float* x = (const float*)d_in[0];
    const int* ei = (const int*)d_in[1];
    const int* et = (const int*)d_in[2];
    const float* mlp_w1 = (const float*)d_in[3];
    const float* mlp_b1 = (const float*)d_in[4];
    const float* mbn1_g = (const float*)d_in[5];
    const float* mbn1_b = (const float*)d_in[6];
    const float* mbn1_m = (const float*)d_in[7];
    const float* mbn1_v = (const float*)d_in[8];
    const float* mlp_w2 = (const float*)d_in[9];
    const float* mlp_b2 = (const float*)d_in[10];
    const float* mbn2_g = (const float*)d_in[11];
    const float* mbn2_b = (const float*)d_in[12];
    const float* mbn2_m = (const float*)d_in[13];
    const float* mbn2_v = (const float*)d_in[14];
    const float* r1_wrel = (const float*)d_in[15];
    const float* r1_wroot = (const float*)d_in[16];
    const float* r1_b = (const float*)d_in[17];
    const float* gbn1_g = (const float*)d_in[18];
    const float* gbn1_b = (const float*)d_in[19];
    const float* gbn1_m = (const float*)d_in[20];
    const float* gbn1_v = (const float*)d_in[21];
    const float* r2_wrel = (const float*)d_in[22];
    const float* r2_wroot = (const float*)d_in[23];
    const float* r2_b = (const float*)d_in[24];
    const float* gbn2_g = (const float*)d_in[25];
    const float* gbn2_b = (const float*)d_in[26];
    const float* gbn2_m = (const float*)d_in[27];
    const float* gbn2_v = (const float*)d_in[28];
    const float* out_w = (const float*)d_in[29];
    const float* out_b = (const float*)d_in[30];

    const int N = in_sizes[0] / 256;
    const int E = in_sizes[2];

    // ---- workspace layout ----
    size_t off = 0;
    auto take = [&](size_t bytes) {
        size_t o = off;
        off = alignup(off + bytes);
        return o;
    };
    char* base = (char*)d_ws;
    // zeroed region: cntR[N], cntRT[3N], cntCT[3N], fillR[N], fillC[3N]
    size_t zeroOff = take((size_t)N * 11 * 4);
    int* cntR = (int*)(base + zeroOff);
    int* cntRT = cntR + N;
    int* cntCT = cntRT + (size_t)N * 3;
    int* fillR = cntCT + (size_t)N * 3;
    int* fillC = fillR + N;
    int* offR = (int*)(base + take((size_t)N * 4));
    int* offC = (int*)(base + take((size_t)N * 3 * 4));
    int* bsums = (int*)(base + take(256 * 4));
    float* sc_r = (float*)(base + take((size_t)N * 3 * 4));
    int* idxR = (int*)(base + take((size_t)E * 4));
    float* coefR = (float*)(base + take((size_t)E * 4));
    int* idxC = (int*)(base + take((size_t)E * 4));
    u16* w1t = (u16*)(base + take((size_t)256 * 256 * 2));
    u16* w2t = (u16*)(base + take((size_t)256 * 256 * 2));
    u16* r1relt = (u16*)(base + take((size_t)256 * 768 * 2));
    u16* r1roott = (u16*)(base + take((size_t)256 * 256 * 2));
    u16* r2relt = (u16*)(base + take((size_t)256 * 768 * 2));
    u16* r2roott = (u16*)(base + take((size_t)256 * 256 * 2));
    u16* regA = (u16*)(base + take((size_t)N * 256 * 2));  // z1_mlp -> h -> z_gnn
    u16* regB = (u16*)(base + take((size_t)N * 256 * 2));  // z_mlp
    u16* regC = (u16*)(base + take((size_t)N * 256 * 2));  // z1_gnn
    size_t chunkOff = off;
    size_t avail = (ws_size > chunkOff) ? ws_size - chunkOff : 0;
    size_t ncap = avail / ((size_t)768 * 2);
    if (ncap < 2048) {
        hipMemsetAsync(d_out, 0, (size_t)out_size * 4, stream);
        return;
    }
    int Nc = (int)((ncap < (size_t)N) ? ncap : (size_t)N);
    int nch = (N + Nc - 1) / Nc;
    Nc = (N + nch - 1) / nch;
    u16* CH = (u16*)(base + chunkOff);  // Nc*768 bf16 means chunk

    // ---- CSR build ----
    hipMemsetAsync(cntR, 0, (size_t)N * 11 * 4, stream);
    k_count<<<(E + 255) / 256, 256, 0, stream>>>(ei, et, cntR, cntRT, cntCT, E);
    k_scales<<<(N + 255) / 256, 256, 0, stream>>>(cntRT, sc_r, N);
    {
        int n1 = N, nb1 = (n1 + 2047) / 2048;
        k_scan1<<<nb1, 256, 0, stream>>>(cntR, offR, bsums, n1);
        k_scan2<<<1, 256, 0, stream>>>(bsums, nb1);
        k_scan3<<<nb1, 256, 0, stream>>>(offR, bsums, n1);
        int n2 = N * 3, nb2 = (n2 + 2047) / 2048;
        k_scan1<<<nb2, 256, 0, stream>>>(cntCT, offC, bsums, n2);
        k_scan2<<<1, 256, 0, stream>>>(bsums, nb2);
        k_scan3<<<nb2, 256, 0, stream>>>(offC, bsums, n2);
    }
    k_scatter<<<(E + 255) / 256, 256, 0, stream>>>(ei, et, sc_r, offR, fillR, idxR,
                                                   coefR, offC, fillC, idxC, E);

    // ---- weight transposes (fp32 -> bf16 [256][K]) ----
    k_wt<<<dim3(8, 8), 256, 0, stream>>>(mlp_w1, w1t, 256);
    k_wt<<<dim3(8, 8), 256, 0, stream>>>(mlp_w2, w2t, 256);
    k_wt<<<dim3(24, 8), 256, 0, stream>>>(r1_wrel, r1relt, 768);
    k_wt<<<dim3(8, 8), 256, 0, stream>>>(r1_wroot, r1roott, 256);
    k_wt<<<dim3(24, 8), 256, 0, stream>>>(r2_wrel, r2relt, 768);
    k_wt<<<dim3(8, 8), 256, 0, stream>>>(r2_wroot, r2roott, 256);

    // ---- MLP branch ----
    {
        dim3 g((N + 127) / 128, 2);
        k_gemm_mfma<1><<<g, 256, 0, stream>>>(x, 256, w1t, nullptr, 0, nullptr,
                                              mlp_b1, mbn1_g, mbn1_b, mbn1_m, mbn1_v,
                                              regA, N);
        k_gemm_mfma<0><<<g, 256, 0, stream>>>(regA, 256, w2t, nullptr, 0, nullptr,
                                              mlp_b2, mbn2_g, mbn2_b, mbn2_m, mbn2_v,
                                              regB, N);
    }

    // ---- SCRE: regA := bf16(h) ----
    k_scre_gather<<<(N + 3) / 4, 256, 0, stream>>>(x, idxR, coefR, offR, cntR, regA, N);

    // ---- RGCN layer 1: regC = relu(bn(means(regA)@wrel + regA@wroot + b)) ----
    for (int ch = 0; ch < nch; ++ch) {
        int n0 = ch * Nc;
        int n1 = (n0 + Nc < N) ? n0 + Nc : N;
        int Mc = n1 - n0;
        int s0 = n0 * 3, s1 = n1 * 3;
        k_rgcn_gather<<<(s1 - s0 + 3) / 4, 256, 0, stream>>>(regA, idxC, offC, cntCT,
                                                             CH, s0, s1);
        dim3 g((Mc + 127) / 128, 2);
        k_gemm_mfma<0><<<g, 256, 0, stream>>>(CH, 768, r1relt,
                                              regA + (size_t)n0 * 256, 256, r1roott,
                                              r1_b, gbn1_g, gbn1_b, gbn1_m, gbn1_v,
                                              regC + (size_t)n0 * 256, Mc);
    }

    // ---- RGCN layer 2: regA = relu(bn(means(regC)@wrel + regC@wroot + b)) ----
    for (int ch = 0; ch < nch; ++ch) {
        int n0 = ch * Nc;
        int n1 = (n0 + Nc < N) ? n0 + Nc : N;
        int Mc = n1 - n0;
        int s0 = n0 * 3, s1 = n1 * 3;
        k_rgcn_gather<<<(s1 - s0 + 3) / 4, 256, 0, stream>>>(regC, idxC, offC, cntCT,
                                                             CH, s0, s1);
        dim3 g((Mc + 127) / 128, 2);
        k_gemm_mfma<0><<<g, 256, 0, stream>>>(CH, 768, r2relt,
                                              regC + (size_t)n0 * 256, 256, r2roott,
                                              r2_b, gbn2_g, gbn2_b, gbn2_m, gbn2_v,
                                              regA + (size_t)n0 * 256, Mc);
    }

    // ---- head ----
    k_head<<<(N + 3) / 4, 256, 0, stream>>>(regB, regA, out_w, out_b, (float*)d_out, N);
}

// Round 6
// 1017.326 us; speedup vs baseline: 6.9806x; 1.0198x over previous
//
#include <hip/hip_runtime.h>

#define BN_EPS 1e-5f

typedef unsigned short u16;
typedef short bf16x8 __attribute__((ext_vector_type(8)));
typedef float f32x4 __attribute__((ext_vector_type(4)));

__device__ __forceinline__ float bf2f(u16 u) {
    return __uint_as_float(((unsigned)u) << 16);
}
__device__ __forceinline__ u16 f2bf(float f) {
    unsigned u = __float_as_uint(f);
    u += 0x7FFFu + ((u >> 16) & 1u);
    return (u16)(u >> 16);
}

// ---------------------------------------------------------------------------
// counts: cntR[r] (edges per row), cntRT[r*3+t], cntCT[c*3+t]
__global__ __launch_bounds__(256) void k_count(const int* __restrict__ ei,
                                               const int* __restrict__ et,
                                               int* __restrict__ cntR,
                                               int* __restrict__ cntRT,
                                               int* __restrict__ cntCT, int E) {
    int e = blockIdx.x * 256 + threadIdx.x;
    if (e >= E) return;
    int r = ei[e], c = ei[E + e], t = et[e];
    atomicAdd(cntR + r, 1);
    atomicAdd(cntRT + (size_t)r * 3 + t, 1);
    atomicAdd(cntCT + (size_t)c * 3 + t, 1);
}

// SCRE folded coefficient: sc_r[n,t] = cnt>0 ? 1/(cnt*relcount(n)) : 0
__global__ __launch_bounds__(256) void k_scales(const int* __restrict__ cntRT,
                                                float* __restrict__ sc_r, int N) {
    int n = blockIdx.x * 256 + threadIdx.x;
    if (n >= N) return;
    int c0 = cntRT[n * 3 + 0], c1 = cntRT[n * 3 + 1], c2 = cntRT[n * 3 + 2];
    float relc = (float)((c0 > 0) + (c1 > 0) + (c2 > 0));
    if (relc < 1.f) relc = 1.f;
    sc_r[n * 3 + 0] = c0 > 0 ? 1.f / ((float)c0 * relc) : 0.f;
    sc_r[n * 3 + 1] = c1 > 0 ? 1.f / ((float)c1 * relc) : 0.f;
    sc_r[n * 3 + 2] = c2 > 0 ? 1.f / ((float)c2 * relc) : 0.f;
}

// ---- exclusive scan (3 kernels); n <= 256*2048 ----
__global__ __launch_bounds__(256) void k_scan1(const int* __restrict__ in,
                                               int* __restrict__ out,
                                               int* __restrict__ bsums, int n) {
    __shared__ int sh[256];
    int t = threadIdx.x, base = blockIdx.x * 2048 + t * 8;
    int v[8];
    int s = 0;
#pragma unroll
    for (int j = 0; j < 8; ++j) {
        int idx = base + j;
        v[j] = idx < n ? in[idx] : 0;
        s += v[j];
    }
    sh[t] = s;
    __syncthreads();
    for (int off = 1; off < 256; off <<= 1) {
        int val = (t >= off) ? sh[t - off] : 0;
        __syncthreads();
        sh[t] += val;
        __syncthreads();
    }
    int run = sh[t] - s;  // exclusive thread base
    if (t == 255) bsums[blockIdx.x] = sh[255];
#pragma unroll
    for (int j = 0; j < 8; ++j) {
        int idx = base + j;
        if (idx < n) out[idx] = run;
        run += v[j];
    }
}
__global__ __launch_bounds__(256) void k_scan2(int* __restrict__ bsums, int nb) {
    __shared__ int sh[256];
    int t = threadIdx.x;
    int v = t < nb ? bsums[t] : 0;
    sh[t] = v;
    __syncthreads();
    for (int off = 1; off < 256; off <<= 1) {
        int val = (t >= off) ? sh[t - off] : 0;
        __syncthreads();
        sh[t] += val;
        __syncthreads();
    }
    if (t < nb) bsums[t] = sh[t] - v;
}
__global__ __launch_bounds__(256) void k_scan3(int* __restrict__ out,
                                               const int* __restrict__ bsums, int n) {
    int i = blockIdx.x * 2048 + threadIdx.x * 8;
    int add = bsums[blockIdx.x];
#pragma unroll
    for (int j = 0; j < 8; ++j)
        if (i + j < n) out[i + j] += add;
}

// scatter edges into both CSRs
__global__ __launch_bounds__(256) void k_scatter(const int* __restrict__ ei,
                                                 const int* __restrict__ et,
                                                 const float* __restrict__ sc_r,
                                                 const int* __restrict__ offR,
                                                 int* __restrict__ fillR,
                                                 int* __restrict__ idxR,
                                                 float* __restrict__ coefR,
                                                 const int* __restrict__ offC,
                                                 int* __restrict__ fillC,
                                                 int* __restrict__ idxC, int E) {
    int e = blockIdx.x * 256 + threadIdx.x;
    if (e >= E) return;
    int r = ei[e], c = ei[E + e], t = et[e];
    int pR = offR[r] + atomicAdd(fillR + r, 1);
    idxR[pR] = c;
    coefR[pR] = sc_r[(size_t)r * 3 + t];
    int key = c * 3 + t;
    int pC = offC[key] + atomicAdd(fillC + key, 1);
    idxC[pC] = r;
}

// SCRE gather: one wave per node; h[n] = bf16(x[n] - sum coef*x[col])
__global__ __launch_bounds__(256) void k_scre_gather(const float* __restrict__ x,
                                                     const int* __restrict__ idxR,
                                                     const float* __restrict__ coefR,
                                                     const int* __restrict__ offR,
                                                     const int* __restrict__ cntR,
                                                     u16* __restrict__ h, int N) {
    int node = blockIdx.x * 4 + (threadIdx.x >> 6);
    if (node >= N) return;
    int lane = threadIdx.x & 63;
    int start = offR[node], len = cntR[node];
    float4 acc = make_float4(0.f, 0.f, 0.f, 0.f);
    for (int i = 0; i < len; ++i) {
        int c = idxR[start + i];
        float s = coefR[start + i];
        float4 v = *reinterpret_cast<const float4*>(x + (size_t)c * 256 + lane * 4);
        acc.x += s * v.x;
        acc.y += s * v.y;
        acc.z += s * v.z;
        acc.w += s * v.w;
    }
    float4 xv = *reinterpret_cast<const float4*>(x + (size_t)node * 256 + lane * 4);
    ushort4 o;
    o.x = f2bf(xv.x - acc.x);
    o.y = f2bf(xv.y - acc.y);
    o.z = f2bf(xv.z - acc.z);
    o.w = f2bf(xv.w - acc.w);
    *reinterpret_cast<ushort4*>(h + (size_t)node * 256 + lane * 4) = o;
}

// RGCN gather: 32 lanes per segment (bf16x8 = 16B/lane), 2 segs/wave, 8 segs/block
__global__ __launch_bounds__(256) void k_rgcn_gather(const u16* __restrict__ src,
                                                     const int* __restrict__ idxC,
                                                     const int* __restrict__ offC,
                                                     const int* __restrict__ cntC,
                                                     u16* __restrict__ means,
                                                     int s0, int s1) {
    int seg = s0 + blockIdx.x * 8 + (threadIdx.x >> 5);
    if (seg >= s1) return;
    int lane = threadIdx.x & 31;
    int start = offC[seg], len = cntC[seg];
    float acc[8] = {};
    for (int i = 0; i < len; ++i) {
        int r = idxC[start + i];
        bf16x8 v = *reinterpret_cast<const bf16x8*>(src + (size_t)r * 256 + lane * 8);
#pragma unroll
        for (int e = 0; e < 8; ++e) acc[e] += bf2f(((u16*)&v)[e]);
    }
    float inv = len > 0 ? 1.f / (float)len : 0.f;
    bf16x8 o;
#pragma unroll
    for (int e = 0; e < 8; ++e) ((u16*)&o)[e] = f2bf(acc[e] * inv);
    *reinterpret_cast<bf16x8*>(means + (size_t)(seg - s0) * 256 + lane * 8) = o;
}

// weight transpose+convert: W[K][256] fp32 -> Wt[256][K] bf16 (32x32 LDS tiles)
__global__ __launch_bounds__(256) void k_wt(const float* __restrict__ W,
                                            u16* __restrict__ Wt, int K) {
    __shared__ float tile[32][33];
    int kb = blockIdx.x * 32, nb = blockIdx.y * 32;
    int tx = threadIdx.x & 31, ty = threadIdx.x >> 5;  // 8 rows per pass
#pragma unroll
    for (int j = 0; j < 4; ++j) {
        int k = kb + ty + j * 8;
        tile[ty + j * 8][tx] = W[(size_t)k * 256 + nb + tx];
    }
    __syncthreads();
#pragma unroll
    for (int j = 0; j < 4; ++j) {
        int n = nb + ty + j * 8;
        Wt[(size_t)n * K + kb + tx] = f2bf(tile[tx][ty + j * 8]);
    }
}

// ---------------------------------------------------------------------------
// MFMA GEMM: out = bf16(relu(BN( [A1|A2] @ [W1t|W2t]^T + bias )))
// Unified K-space (K1 then K2). Tile 128(M) x 256(N, full width), 256 thr =
// 4 waves (2x2), wave computes 64x128 via acc[4][8] f32x4. Double-buffered
// LDS (one barrier per 32-k step), reg-staged with issue-early prefetch.
// LDS K-stride LDK=40 (80B) -> 2-way bank aliasing on b128 reads (free).
#define LDK 40
#define BM 128

template <int A1_F32>
__global__ __launch_bounds__(256) void k_gemm_mfma(
    const void* __restrict__ A1v, int K1, const u16* __restrict__ W1t,
    const u16* __restrict__ A2, int K2, const u16* __restrict__ W2t,
    const float* __restrict__ bias,
    const float* __restrict__ bng, const float* __restrict__ bnb,
    const float* __restrict__ bnm, const float* __restrict__ bnv,
    u16* __restrict__ out, int M) {
    __shared__ u16 Asm[2][BM * LDK];
    __shared__ u16 Bsm[2][256 * LDK];
    const int tid = threadIdx.x;
    const int lane = tid & 63;
    const int wid = tid >> 6;
    const int wr = wid >> 1, wc = wid & 1;
    const int m0 = blockIdx.x * BM;
    const int frow = lane & 15, fk = (lane >> 4) * 8;
    const int arow = tid >> 2;          // 0..63
    const int achunk = (tid & 3) * 8;   // k-offset in elems

    const int nsteps = (K1 + K2) >> 5;

    f32x4 acc[4][8] = {};
    bf16x8 pa[2], pb[4];

    // ---- prologue: stage k-step 0 into regs ----
    {
        const int kg = 0;
#pragma unroll
        for (int s = 0; s < 2; ++s) {
            int gm = m0 + arow + 64 * s;
            bf16x8 v = {};
            if (gm < M) {
                if (A1_F32) {
                    const float* p = (const float*)A1v + (size_t)gm * K1 + kg + achunk;
#pragma unroll
                    for (int e = 0; e < 8; ++e) ((u16*)&v)[e] = f2bf(p[e]);
                } else {
                    v = *reinterpret_cast<const bf16x8*>((const u16*)A1v + (size_t)gm * K1 + kg + achunk);
                }
            }
            pa[s] = v;
        }
#pragma unroll
        for (int s = 0; s < 4; ++s)
            pb[s] = *reinterpret_cast<const bf16x8*>(W1t + (size_t)(arow + 64 * s) * K1 + kg + achunk);
    }

    int cur = 0;
    for (int ks = 0; ks < nsteps; ++ks) {
        // write staged regs to LDS buf[cur]
#pragma unroll
        for (int s = 0; s < 2; ++s)
            *reinterpret_cast<bf16x8*>(&Asm[cur][(arow + 64 * s) * LDK + achunk]) = pa[s];
#pragma unroll
        for (int s = 0; s < 4; ++s)
            *reinterpret_cast<bf16x8*>(&Bsm[cur][(arow + 64 * s) * LDK + achunk]) = pb[s];
        __syncthreads();

        // issue next step's global loads (overlaps with MFMA below)
        if (ks + 1 < nsteps) {
            const int kg = (ks + 1) * 32;
#pragma unroll
            for (int s = 0; s < 2; ++s) {
                int gm = m0 + arow + 64 * s;
                bf16x8 v = {};
                if (gm < M) {
                    if (kg < K1) {
                        if (A1_F32) {
                            const float* p = (const float*)A1v + (size_t)gm * K1 + kg + achunk;
#pragma unroll
                            for (int e = 0; e < 8; ++e) ((u16*)&v)[e] = f2bf(p[e]);
                        } else {
                            v = *reinterpret_cast<const bf16x8*>((const u16*)A1v + (size_t)gm * K1 + kg + achunk);
                        }
                    } else {
                        v = *reinterpret_cast<const bf16x8*>(A2 + (size_t)gm * K2 + (kg - K1) + achunk);
                    }
                }
                pa[s] = v;
            }
#pragma unroll
            for (int s = 0; s < 4; ++s) {
                int row = arow + 64 * s;
                if (kg < K1)
                    pb[s] = *reinterpret_cast<const bf16x8*>(W1t + (size_t)row * K1 + kg + achunk);
                else
                    pb[s] = *reinterpret_cast<const bf16x8*>(W2t + (size_t)row * K2 + (kg - K1) + achunk);
            }
        }

        // compute from buf[cur]
        bf16x8 af[4];
#pragma unroll
        for (int i = 0; i < 4; ++i)
            af[i] = *reinterpret_cast<const bf16x8*>(&Asm[cur][(wr * 64 + i * 16 + frow) * LDK + fk]);
#pragma unroll
        for (int j = 0; j < 8; ++j) {
            bf16x8 bfr = *reinterpret_cast<const bf16x8*>(&Bsm[cur][(wc * 128 + j * 16 + frow) * LDK + fk]);
#pragma unroll
            for (int i = 0; i < 4; ++i)
                acc[i][j] = __builtin_amdgcn_mfma_f32_16x16x32_bf16(af[i], bfr, acc[i][j], 0, 0, 0);
        }
        cur ^= 1;
        // no trailing barrier needed: next iter's writes go to buf[cur^1];
        // reuse of this buf happens after the next iteration's mid-barrier.
    }

    // epilogue: C/D frag layout col=lane&15, row=(lane>>4)*4+j [m89-verified]
    const int crow = (lane >> 4) * 4;
#pragma unroll
    for (int fj = 0; fj < 8; ++fj) {
        int col = wc * 128 + fj * 16 + frow;
        float g = bng[col] * rsqrtf(bnv[col] + BN_EPS);
        float be = bnb[col] + (bias[col] - bnm[col]) * g;
#pragma unroll
        for (int fi = 0; fi < 4; ++fi) {
#pragma unroll
            for (int j = 0; j < 4; ++j) {
                int row = m0 + wr * 64 + fi * 16 + crow + j;
                if (row < M) {
                    float y = acc[fi][fj][j] * g + be;
                    out[(size_t)row * 256 + col] = f2bf(y > 0.f ? y : 0.f);
                }
            }
        }
    }
}

// head: out[n] = dot(zm[n], ow[0:256]) + dot(zg[n], ow[256:512]) + ob
__global__ __launch_bounds__(256) void k_head(const u16* __restrict__ zm,
                                              const u16* __restrict__ zg,
                                              const float* __restrict__ ow,
                                              const float* __restrict__ ob,
                                              float* __restrict__ out, int N) {
    int n = blockIdx.x * 4 + (threadIdx.x >> 6);
    if (n >= N) return;
    int lane = threadIdx.x & 63;
    ushort4 a = *reinterpret_cast<const ushort4*>(zm + (size_t)n * 256 + lane * 4);
    float4 w = *reinterpret_cast<const float4*>(ow + lane * 4);
    float s = bf2f(a.x) * w.x + bf2f(a.y) * w.y + bf2f(a.z) * w.z + bf2f(a.w) * w.w;
    ushort4 b = *reinterpret_cast<const ushort4*>(zg + (size_t)n * 256 + lane * 4);
    float4 w2 = *reinterpret_cast<const float4*>(ow + 256 + lane * 4);
    s += bf2f(b.x) * w2.x + bf2f(b.y) * w2.y + bf2f(b.z) * w2.z + bf2f(b.w) * w2.w;
#pragma unroll
    for (int off = 32; off > 0; off >>= 1) s += __shfl_down(s, off);
    if (lane == 0) out[n] = s + ob[0];
}

// ---------------------------------------------------------------------------
static inline size_t alignup(size_t x) { return (x + 255) & ~(size_t)255; }

extern "C" void kernel_launch(void* const* d_in, const int* in_sizes, int n_in,
                              void* d_out, int out_size, void* d_ws, size_t ws_size,
                              hipStream_t stream) {
    const float* x = (const float*)d_in[0];
    const int* ei = (const int*)d_in[1];
    const int* et = (const int*)d_in[2];
    const float* mlp_w1 = (const float*)d_in[3];
    const float* mlp_b1 = (const float*)d_in[4];
    const float* mbn1_g = (const float*)d_in[5];
    const float* mbn1_b = (const float*)d_in[6];
    const float* mbn1_m = (const float*)d_in[7];
    const float* mbn1_v = (const float*)d_in[8];
    const float* mlp_w2 = (const float*)d_in[9];
    const float* mlp_b2 = (const float*)d_in[10];
    const float* mbn2_g = (const float*)d_in[11];
    const float* mbn2_b = (const float*)d_in[12];
    const float* mbn2_m = (const float*)d_in[13];
    const float* mbn2_v = (const float*)d_in[14];
    const float* r1_wrel = (const float*)d_in[15];
    const float* r1_wroot = (const float*)d_in[16];
    const float* r1_b = (const float*)d_in[17];
    const float* gbn1_g = (const float*)d_in[18];
    const float* gbn1_b = (const float*)d_in[19];
    const float* gbn1_m = (const float*)d_in[20];
    const float* gbn1_v = (const float*)d_in[21];
    const float* r2_wrel = (const float*)d_in[22];
    const float* r2_wroot = (const float*)d_in[23];
    const float* r2_b = (const float*)d_in[24];
    const float* gbn2_g = (const float*)d_in[25];
    const float* gbn2_b = (const float*)d_in[26];
    const float* gbn2_m = (const float*)d_in[27];
    const float* gbn2_v = (const float*)d_in[28];
    const float* out_w = (const float*)d_in[29];
    const float* out_b = (const float*)d_in[30];

    const int N = in_sizes[0] / 256;
    const int E = in_sizes[2];

    // ---- workspace layout ----
    size_t off = 0;
    auto take = [&](size_t bytes) {
        size_t o = off;
        off = alignup(off + bytes);
        return o;
    };
    char* base = (char*)d_ws;
    // zeroed region: cntR[N], cntRT[3N], cntCT[3N], fillR[N], fillC[3N]
    size_t zeroOff = take((size_t)N * 11 * 4);
    int* cntR = (int*)(base + zeroOff);
    int* cntRT = cntR + N;
    int* cntCT = cntRT + (size_t)N * 3;
    int* fillR = cntCT + (size_t)N * 3;
    int* fillC = fillR + N;
    int* offR = (int*)(base + take((size_t)N * 4));
    int* offC = (int*)(base + take((size_t)N * 3 * 4));
    int* bsums = (int*)(base + take(256 * 4));
    float* sc_r = (float*)(base + take((size_t)N * 3 * 4));
    int* idxR = (int*)(base + take((size_t)E * 4));
    float* coefR = (float*)(base + take((size_t)E * 4));
    int* idxC = (int*)(base + take((size_t)E * 4));
    u16* w1t = (u16*)(base + take((size_t)256 * 256 * 2));
    u16* w2t = (u16*)(base + take((size_t)256 * 256 * 2));
    u16* r1relt = (u16*)(base + take((size_t)256 * 768 * 2));
    u16* r1roott = (u16*)(base + take((size_t)256 * 256 * 2));
    u16* r2relt = (u16*)(base + take((size_t)256 * 768 * 2));
    u16* r2roott = (u16*)(base + take((size_t)256 * 256 * 2));
    u16* regA = (u16*)(base + take((size_t)N * 256 * 2));  // z1_mlp -> h -> z_gnn
    u16* regB = (u16*)(base + take((size_t)N * 256 * 2));  // z_mlp
    u16* regC = (u16*)(base + take((size_t)N * 256 * 2));  // z1_gnn
    size_t chunkOff = off;
    size_t avail = (ws_size > chunkOff) ? ws_size - chunkOff : 0;
    size_t ncap = avail / ((size_t)768 * 2);
    if (ncap < 2048) {
        hipMemsetAsync(d_out, 0, (size_t)out_size * 4, stream);
        return;
    }
    int Nc = (int)((ncap < (size_t)N) ? ncap : (size_t)N);
    int nch = (N + Nc - 1) / Nc;
    Nc = (N + nch - 1) / nch;
    u16* CH = (u16*)(base + chunkOff);  // Nc*768 bf16 means chunk

    // ---- CSR build ----
    hipMemsetAsync(cntR, 0, (size_t)N * 11 * 4, stream);
    k_count<<<(E + 255) / 256, 256, 0, stream>>>(ei, et, cntR, cntRT, cntCT, E);
    k_scales<<<(N + 255) / 256, 256, 0, stream>>>(cntRT, sc_r, N);
    {
        int n1 = N, nb1 = (n1 + 2047) / 2048;
        k_scan1<<<nb1, 256, 0, stream>>>(cntR, offR, bsums, n1);
        k_scan2<<<1, 256, 0, stream>>>(bsums, nb1);
        k_scan3<<<nb1, 256, 0, stream>>>(offR, bsums, n1);
        int n2 = N * 3, nb2 = (n2 + 2047) / 2048;
        k_scan1<<<nb2, 256, 0, stream>>>(cntCT, offC, bsums, n2);
        k_scan2<<<1, 256, 0, stream>>>(bsums, nb2);
        k_scan3<<<nb2, 256, 0, stream>>>(offC, bsums, n2);
    }
    k_scatter<<<(E + 255) / 256, 256, 0, stream>>>(ei, et, sc_r, offR, fillR, idxR,
                                                   coefR, offC, fillC, idxC, E);

    // ---- weight transposes (fp32 -> bf16 [256][K]) ----
    k_wt<<<dim3(8, 8), 256, 0, stream>>>(mlp_w1, w1t, 256);
    k_wt<<<dim3(8, 8), 256, 0, stream>>>(mlp_w2, w2t, 256);
    k_wt<<<dim3(24, 8), 256, 0, stream>>>(r1_wrel, r1relt, 768);
    k_wt<<<dim3(8, 8), 256, 0, stream>>>(r1_wroot, r1roott, 256);
    k_wt<<<dim3(24, 8), 256, 0, stream>>>(r2_wrel, r2relt, 768);
    k_wt<<<dim3(8, 8), 256, 0, stream>>>(r2_wroot, r2roott, 256);

    // ---- MLP branch ----
    {
        dim3 g((N + 127) / 128);
        k_gemm_mfma<1><<<g, 256, 0, stream>>>(x, 256, w1t, nullptr, 0, nullptr,
                                              mlp_b1, mbn1_g, mbn1_b, mbn1_m, mbn1_v,
                                              regA, N);
        k_gemm_mfma<0><<<g, 256, 0, stream>>>(regA, 256, w2t, nullptr, 0, nullptr,
                                              mlp_b2, mbn2_g, mbn2_b, mbn2_m, mbn2_v,
                                              regB, N);
    }

    // ---- SCRE: regA := bf16(h) ----
    k_scre_gather<<<(N + 3) / 4, 256, 0, stream>>>(x, idxR, coefR, offR, cntR, regA, N);

    // ---- RGCN layer 1: regC = relu(bn(means(regA)@wrel + regA@wroot + b)) ----
    for (int ch = 0; ch < nch; ++ch) {
        int n0 = ch * Nc;
        int n1 = (n0 + Nc < N) ? n0 + Nc : N;
        int Mc = n1 - n0;
        int s0 = n0 * 3, s1 = n1 * 3;
        k_rgcn_gather<<<(s1 - s0 + 7) / 8, 256, 0, stream>>>(regA, idxC, offC, cntCT,
                                                             CH, s0, s1);
        dim3 g((Mc + 127) / 128);
        k_gemm_mfma<0><<<g, 256, 0, stream>>>(CH, 768, r1relt,
                                              regA + (size_t)n0 * 256, 256, r1roott,
                                              r1_b, gbn1_g, gbn1_b, gbn1_m, gbn1_v,
                                              regC + (size_t)n0 * 256, Mc);
    }

    // ---- RGCN layer 2: regA = relu(bn(means(regC)@wrel + regC@wroot + b)) ----
    for (int ch = 0; ch < nch; ++ch) {
        int n0 = ch * Nc;
        int n1 = (n0 + Nc < N) ? n0 + Nc : N;
        int Mc = n1 - n0;
        int s0 = n0 * 3, s1 = n1 * 3;
        k_rgcn_gather<<<(s1 - s0 + 7) / 8, 256, 0, stream>>>(regC, idxC, offC, cntCT,
                                                             CH, s0, s1);
        dim3 g((Mc + 127) / 128);
        k_gemm_mfma<0><<<g, 256, 0, stream>>>(CH, 768, r2relt,
                                              regC + (size_t)n0 * 256, 256, r2roott,
                                              r2_b, gbn2_g, gbn2_b, gbn2_m, gbn2_v,
                                              regA + (size_t)n0 * 256, Mc);
    }

    // ---- head ----
    k_head<<<(N + 3) / 4, 256, 0, stream>>>(regB, regA, out_w, out_b, (float*)d_out, N);
}

// Round 9
// 879.622 us; speedup vs baseline: 8.0734x; 1.1565x over previous
//
#include <hip/hip_runtime.h>

#define BN_EPS 1e-5f

typedef unsigned short u16;
typedef short bf16x8 __attribute__((ext_vector_type(8)));
typedef float f32x4 __attribute__((ext_vector_type(4)));

__device__ __forceinline__ float bf2f(u16 u) {
    return __uint_as_float(((unsigned)u) << 16);
}
__device__ __forceinline__ u16 f2bf(float f) {
    unsigned u = __float_as_uint(f);
    u += 0x7FFFu + ((u >> 16) & 1u);
    return (u16)(u >> 16);
}

// ---------------------------------------------------------------------------
// x (fp32) -> x_bf (bf16), 8 elems/thread
__global__ __launch_bounds__(256) void k_xbf(const float* __restrict__ x,
                                             u16* __restrict__ xb, int n8) {
    int i = blockIdx.x * 256 + threadIdx.x;
    if (i >= n8) return;
    const float4 a = *reinterpret_cast<const float4*>(x + (size_t)i * 8);
    const float4 b = *reinterpret_cast<const float4*>(x + (size_t)i * 8 + 4);
    bf16x8 o;
    ((u16*)&o)[0] = f2bf(a.x);
    ((u16*)&o)[1] = f2bf(a.y);
    ((u16*)&o)[2] = f2bf(a.z);
    ((u16*)&o)[3] = f2bf(a.w);
    ((u16*)&o)[4] = f2bf(b.x);
    ((u16*)&o)[5] = f2bf(b.y);
    ((u16*)&o)[6] = f2bf(b.z);
    ((u16*)&o)[7] = f2bf(b.w);
    *reinterpret_cast<bf16x8*>(xb + (size_t)i * 8) = o;
}

// counts: cntR[r] (edges per row), cntRT[r*3+t], cntCT[c*3+t]
__global__ __launch_bounds__(256) void k_count(const int* __restrict__ ei,
                                               const int* __restrict__ et,
                                               int* __restrict__ cntR,
                                               int* __restrict__ cntRT,
                                               int* __restrict__ cntCT, int E) {
    int e = blockIdx.x * 256 + threadIdx.x;
    if (e >= E) return;
    int r = ei[e], c = ei[E + e], t = et[e];
    atomicAdd(cntR + r, 1);
    atomicAdd(cntRT + (size_t)r * 3 + t, 1);
    atomicAdd(cntCT + (size_t)c * 3 + t, 1);
}

// SCRE folded coefficient: sc_r[n,t] = cnt>0 ? 1/(cnt*relcount(n)) : 0
__global__ __launch_bounds__(256) void k_scales(const int* __restrict__ cntRT,
                                                float* __restrict__ sc_r, int N) {
    int n = blockIdx.x * 256 + threadIdx.x;
    if (n >= N) return;
    int c0 = cntRT[n * 3 + 0], c1 = cntRT[n * 3 + 1], c2 = cntRT[n * 3 + 2];
    float relc = (float)((c0 > 0) + (c1 > 0) + (c2 > 0));
    if (relc < 1.f) relc = 1.f;
    sc_r[n * 3 + 0] = c0 > 0 ? 1.f / ((float)c0 * relc) : 0.f;
    sc_r[n * 3 + 1] = c1 > 0 ? 1.f / ((float)c1 * relc) : 0.f;
    sc_r[n * 3 + 2] = c2 > 0 ? 1.f / ((float)c2 * relc) : 0.f;
}

// ---- exclusive scan (3 kernels); n <= 256*2048 ----
__global__ __launch_bounds__(256) void k_scan1(const int* __restrict__ in,
                                               int* __restrict__ out,
                                               int* __restrict__ bsums, int n) {
    __shared__ int sh[256];
    int t = threadIdx.x, base = blockIdx.x * 2048 + t * 8;
    int v[8];
    int s = 0;
#pragma unroll
    for (int j = 0; j < 8; ++j) {
        int idx = base + j;
        v[j] = idx < n ? in[idx] : 0;
        s += v[j];
    }
    sh[t] = s;
    __syncthreads();
    for (int off = 1; off < 256; off <<= 1) {
        int val = (t >= off) ? sh[t - off] : 0;
        __syncthreads();
        sh[t] += val;
        __syncthreads();
    }
    int run = sh[t] - s;  // exclusive thread base
    if (t == 255) bsums[blockIdx.x] = sh[255];
#pragma unroll
    for (int j = 0; j < 8; ++j) {
        int idx = base + j;
        if (idx < n) out[idx] = run;
        run += v[j];
    }
}
__global__ __launch_bounds__(256) void k_scan2(int* __restrict__ bsums, int nb) {
    __shared__ int sh[256];
    int t = threadIdx.x;
    int v = t < nb ? bsums[t] : 0;
    sh[t] = v;
    __syncthreads();
    for (int off = 1; off < 256; off <<= 1) {
        int val = (t >= off) ? sh[t - off] : 0;
        __syncthreads();
        sh[t] += val;
        __syncthreads();
    }
    if (t < nb) bsums[t] = sh[t] - v;
}
__global__ __launch_bounds__(256) void k_scan3(int* __restrict__ out,
                                               const int* __restrict__ bsums, int n) {
    int i = blockIdx.x * 2048 + threadIdx.x * 8;
    int add = bsums[blockIdx.x];
#pragma unroll
    for (int j = 0; j < 8; ++j)
        if (i + j < n) out[i + j] += add;
}

// scatter edges into both CSRs
__global__ __launch_bounds__(256) void k_scatter(const int* __restrict__ ei,
                                                 const int* __restrict__ et,
                                                 const float* __restrict__ sc_r,
                                                 const int* __restrict__ offR,
                                                 int* __restrict__ fillR,
                                                 int* __restrict__ idxR,
                                                 float* __restrict__ coefR,
                                                 const int* __restrict__ offC,
                                                 int* __restrict__ fillC,
                                                 int* __restrict__ idxC, int E) {
    int e = blockIdx.x * 256 + threadIdx.x;
    if (e >= E) return;
    int r = ei[e], c = ei[E + e], t = et[e];
    int pR = offR[r] + atomicAdd(fillR + r, 1);
    idxR[pR] = c;
    coefR[pR] = sc_r[(size_t)r * 3 + t];
    int key = c * 3 + t;
    int pC = offC[key] + atomicAdd(fillC + key, 1);
    idxC[pC] = r;
}

// SCRE gather (bf16 src): 32 lanes/node, h[n] = bf16(x[n] - sum coef*x[col])
__global__ __launch_bounds__(256) void k_scre_gather(const u16* __restrict__ xb,
                                                     const int* __restrict__ idxR,
                                                     const float* __restrict__ coefR,
                                                     const int* __restrict__ offR,
                                                     const int* __restrict__ cntR,
                                                     u16* __restrict__ h, int N) {
    int node = blockIdx.x * 8 + (threadIdx.x >> 5);
    if (node >= N) return;
    int lane = threadIdx.x & 31;
    int start = offR[node], len = cntR[node];
    float acc[8] = {};
    for (int i = 0; i < len; ++i) {
        int c = idxR[start + i];
        float s = coefR[start + i];
        bf16x8 v = *reinterpret_cast<const bf16x8*>(xb + (size_t)c * 256 + lane * 8);
#pragma unroll
        for (int e = 0; e < 8; ++e) acc[e] += s * bf2f(((u16*)&v)[e]);
    }
    bf16x8 xv = *reinterpret_cast<const bf16x8*>(xb + (size_t)node * 256 + lane * 8);
    bf16x8 o;
#pragma unroll
    for (int e = 0; e < 8; ++e) ((u16*)&o)[e] = f2bf(bf2f(((u16*)&xv)[e]) - acc[e]);
    *reinterpret_cast<bf16x8*>(h + (size_t)node * 256 + lane * 8) = o;
}

// RGCN gather: 32 lanes per segment (bf16x8 = 16B/lane), 8 segs/block
__global__ __launch_bounds__(256) void k_rgcn_gather(const u16* __restrict__ src,
                                                     const int* __restrict__ idxC,
                                                     const int* __restrict__ offC,
                                                     const int* __restrict__ cntC,
                                                     u16* __restrict__ means,
                                                     int s0, int s1) {
    int seg = s0 + blockIdx.x * 8 + (threadIdx.x >> 5);
    if (seg >= s1) return;
    int lane = threadIdx.x & 31;
    int start = offC[seg], len = cntC[seg];
    float acc[8] = {};
    for (int i = 0; i < len; ++i) {
        int r = idxC[start + i];
        bf16x8 v = *reinterpret_cast<const bf16x8*>(src + (size_t)r * 256 + lane * 8);
#pragma unroll
        for (int e = 0; e < 8; ++e) acc[e] += bf2f(((u16*)&v)[e]);
    }
    float inv = len > 0 ? 1.f / (float)len : 0.f;
    bf16x8 o;
#pragma unroll
    for (int e = 0; e < 8; ++e) ((u16*)&o)[e] = f2bf(acc[e] * inv);
    *reinterpret_cast<bf16x8*>(means + (size_t)(seg - s0) * 256 + lane * 8) = o;
}

// weight transpose+convert: W[K][256] fp32 -> Wt[256][K] bf16 (32x32 LDS tiles)
__global__ __launch_bounds__(256) void k_wt(const float* __restrict__ W,
                                            u16* __restrict__ Wt, int K) {
    __shared__ float tile[32][33];
    int kb = blockIdx.x * 32, nb = blockIdx.y * 32;
    int tx = threadIdx.x & 31, ty = threadIdx.x >> 5;  // 8 rows per pass
#pragma unroll
    for (int j = 0; j < 4; ++j) {
        int k = kb + ty + j * 8;
        tile[ty + j * 8][tx] = W[(size_t)k * 256 + nb + tx];
    }
    __syncthreads();
#pragma unroll
    for (int j = 0; j < 4; ++j) {
        int n = nb + ty + j * 8;
        Wt[(size_t)n * K + kb + tx] = f2bf(tile[tx][ty + j * 8]);
    }
}

// ---------------------------------------------------------------------------
// MFMA GEMM (round-4 proven structure): out = bf16(relu(BN(A1@W1t^T + A2@W2t^T + b)))
// All-bf16 A. 128x128 tile, grid (ceil(M/128), 2), 256 thr = 4 waves (2x2),
// wave = 64x64 via acc[4][4]. Single-buffer LDS, 2 barriers/step, reg-staged
// loads issued before first barrier. LDK=40 pad -> 2-way LDS aliasing (free).
#define LDK 40

__global__ __launch_bounds__(256) void k_gemm_mfma(
    const u16* __restrict__ A1, int K1, const u16* __restrict__ W1t,
    const u16* __restrict__ A2, int K2, const u16* __restrict__ W2t,
    const float* __restrict__ bias,
    const float* __restrict__ bng, const float* __restrict__ bnb,
    const float* __restrict__ bnm, const float* __restrict__ bnv,
    u16* __restrict__ out, int M) {
    __shared__ u16 Asm[128 * LDK];
    __shared__ u16 Bsm[128 * LDK];
    const int tid = threadIdx.x;
    const int lane = tid & 63;
    const int wid = tid >> 6;
    const int wr = wid >> 1, wc = wid & 1;
    const int m0 = blockIdx.x * 128, n0 = blockIdx.y * 128;
    const int frow = lane & 15, fk = (lane >> 4) * 8;

    f32x4 acc[4][4] = {};

    for (int pass = 0; pass < 2; ++pass) {
        const int K = pass ? K2 : K1;
        if (K == 0) continue;
        const u16* A = pass ? A2 : A1;
        const u16* Wt = pass ? W2t : W1t;
        for (int k0 = 0; k0 < K; k0 += 32) {
            bf16x8 av[2], wv[2];
#pragma unroll
            for (int j = 0; j < 2; ++j) {
                int q = tid + 256 * j;
                int row = q >> 2, kc = (q & 3) * 8;
                int gm = m0 + row;
                bf16x8 v = {};
                if (gm < M)
                    v = *reinterpret_cast<const bf16x8*>(A + (size_t)gm * K + k0 + kc);
                av[j] = v;
                wv[j] = *reinterpret_cast<const bf16x8*>(Wt + (size_t)(n0 + row) * K + k0 + kc);
            }
            __syncthreads();
#pragma unroll
            for (int j = 0; j < 2; ++j) {
                int q = tid + 256 * j;
                int row = q >> 2, kc = (q & 3) * 8;
                *reinterpret_cast<bf16x8*>(&Asm[row * LDK + kc]) = av[j];
                *reinterpret_cast<bf16x8*>(&Bsm[row * LDK + kc]) = wv[j];
            }
            __syncthreads();
            bf16x8 af[4], bfr[4];
#pragma unroll
            for (int i = 0; i < 4; ++i) {
                af[i] = *reinterpret_cast<const bf16x8*>(&Asm[(wr * 64 + i * 16 + frow) * LDK + fk]);
                bfr[i] = *reinterpret_cast<const bf16x8*>(&Bsm[(wc * 64 + i * 16 + frow) * LDK + fk]);
            }
#pragma unroll
            for (int i = 0; i < 4; ++i)
#pragma unroll
                for (int j2 = 0; j2 < 4; ++j2)
                    acc[i][j2] = __builtin_amdgcn_mfma_f32_16x16x32_bf16(af[i], bfr[j2], acc[i][j2], 0, 0, 0);
        }
    }

    // epilogue: C/D frag layout col=lane&15, row=(lane>>4)*4+j [m89-verified]
    const int crow = (lane >> 4) * 4;
#pragma unroll
    for (int fj = 0; fj < 4; ++fj) {
        int col = n0 + wc * 64 + fj * 16 + frow;
        float g = bng[col] * rsqrtf(bnv[col] + BN_EPS);
        float be = bnb[col] + (bias[col] - bnm[col]) * g;
#pragma unroll
        for (int fi = 0; fi < 4; ++fi) {
#pragma unroll
            for (int j = 0; j < 4; ++j) {
                int row = m0 + wr * 64 + fi * 16 + crow + j;
                if (row < M) {
                    float y = acc[fi][fj][j] * g + be;
                    out[(size_t)row * 256 + col] = f2bf(y > 0.f ? y : 0.f);
                }
            }
        }
    }
}

// head: out[n] = dot(zm[n], ow[0:256]) + dot(zg[n], ow[256:512]) + ob
__global__ __launch_bounds__(256) void k_head(const u16* __restrict__ zm,
                                              const u16* __restrict__ zg,
                                              const float* __restrict__ ow,
                                              const float* __restrict__ ob,
                                              float* __restrict__ out, int N) {
    int n = blockIdx.x * 4 + (threadIdx.x >> 6);
    if (n >= N) return;
    int lane = threadIdx.x & 63;
    ushort4 a = *reinterpret_cast<const ushort4*>(zm + (size_t)n * 256 + lane * 4);
    float4 w = *reinterpret_cast<const float4*>(ow + lane * 4);
    float s = bf2f(a.x) * w.x + bf2f(a.y) * w.y + bf2f(a.z) * w.z + bf2f(a.w) * w.w;
    ushort4 b = *reinterpret_cast<const ushort4*>(zg + (size_t)n * 256 + lane * 4);
    float4 w2 = *reinterpret_cast<const float4*>(ow + 256 + lane * 4);
    s += bf2f(b.x) * w2.x + bf2f(b.y) * w2.y + bf2f(b.z) * w2.z + bf2f(b.w) * w2.w;
#pragma unroll
    for (int off = 32; off > 0; off >>= 1) s += __shfl_down(s, off);
    if (lane == 0) out[n] = s + ob[0];
}

// ---------------------------------------------------------------------------
static inline size_t alignup(size_t x) { return (x + 255) & ~(size_t)255; }

extern "C" void kernel_launch(void* const* d_in, const int* in_sizes, int n_in,
                              void* d_out, int out_size, void* d_ws, size_t ws_size,
                              hipStream_t stream) {
    const float* x = (const float*)d_in[0];
    const int* ei = (const int*)d_in[1];
    const int* et = (const int*)d_in[2];
    const float* mlp_w1 = (const float*)d_in[3];
    const float* mlp_b1 = (const float*)d_in[4];
    const float* mbn1_g = (const float*)d_in[5];
    const float* mbn1_b = (const float*)d_in[6];
    const float* mbn1_m = (const float*)d_in[7];
    const float* mbn1_v = (const float*)d_in[8];
    const float* mlp_w2 = (const float*)d_in[9];
    const float* mlp_b2 = (const float*)d_in[10];
    const float* mbn2_g = (const float*)d_in[11];
    const float* mbn2_b = (const float*)d_in[12];
    const float* mbn2_m = (const float*)d_in[13];
    const float* mbn2_v = (const float*)d_in[14];
    const float* r1_wrel = (const float*)d_in[15];
    const float* r1_wroot = (const float*)d_in[16];
    const float* r1_b = (const float*)d_in[17];
    const float* gbn1_g = (const float*)d_in[18];
    const float* gbn1_b = (const float*)d_in[19];
    const float* gbn1_m = (const float*)d_in[20];
    const float* gbn1_v = (const float*)d_in[21];
    const float* r2_wrel = (const float*)d_in[22];
    const float* r2_wroot = (const float*)d_in[23];
    const float* r2_b = (const float*)d_in[24];
    const float* gbn2_g = (const float*)d_in[25];
    const float* gbn2_b = (const float*)d_in[26];
    const float* gbn2_m = (const float*)d_in[27];
    const float* gbn2_v = (const float*)d_in[28];
    const float* out_w = (const float*)d_in[29];
    const float* out_b = (const float*)d_in[30];

    const int N = in_sizes[0] / 256;
    const int E = in_sizes[2];

    // ---- workspace layout ----
    size_t off = 0;
    auto take = [&](size_t bytes) {
        size_t o = off;
        off = alignup(off + bytes);
        return o;
    };
    char* base = (char*)d_ws;
    // zeroed region: cntR[N], cntRT[3N], cntCT[3N], fillR[N], fillC[3N]
    size_t zeroOff = take((size_t)N * 11 * 4);
    int* cntR = (int*)(base + zeroOff);
    int* cntRT = cntR + N;
    int* cntCT = cntRT + (size_t)N * 3;
    int* fillR = cntCT + (size_t)N * 3;
    int* fillC = fillR + N;
    int* offR = (int*)(base + take((size_t)N * 4));
    int* offC = (int*)(base + take((size_t)N * 3 * 4));
    int* bsums = (int*)(base + take(256 * 4));
    float* sc_r = (float*)(base + take((size_t)N * 3 * 4));
    int* idxR = (int*)(base + take((size_t)E * 4));
    float* coefR = (float*)(base + take((size_t)E * 4));
    int* idxC = (int*)(base + take((size_t)E * 4));
    u16* w1t = (u16*)(base + take((size_t)256 * 256 * 2));
    u16* w2t = (u16*)(base + take((size_t)256 * 256 * 2));
    u16* r1relt = (u16*)(base + take((size_t)256 * 768 * 2));
    u16* r1roott = (u16*)(base + take((size_t)256 * 256 * 2));
    u16* r2relt = (u16*)(base + take((size_t)256 * 768 * 2));
    u16* r2roott = (u16*)(base + take((size_t)256 * 256 * 2));
    u16* xb = (u16*)(base + take((size_t)N * 256 * 2));    // x in bf16
    u16* regA = (u16*)(base + take((size_t)N * 256 * 2));  // z1_mlp -> h -> z_gnn
    u16* regB = (u16*)(base + take((size_t)N * 256 * 2));  // z_mlp
    u16* regC = (u16*)(base + take((size_t)N * 256 * 2));  // z1_gnn
    size_t chunkOff = off;
    size_t avail = (ws_size > chunkOff) ? ws_size - chunkOff : 0;
    size_t ncap = avail / ((size_t)768 * 2);
    if (ncap < 2048) {
        hipMemsetAsync(d_out, 0, (size_t)out_size * 4, stream);
        return;
    }
    int Nc = (int)((ncap < (size_t)N) ? ncap : (size_t)N);
    int nch = (N + Nc - 1) / Nc;
    Nc = (N + nch - 1) / nch;
    u16* CH = (u16*)(base + chunkOff);  // Nc*768 bf16 means chunk

    // ---- x -> bf16 ----
    k_xbf<<<(N * 32 + 255) / 256, 256, 0, stream>>>(x, xb, N * 32);

    // ---- CSR build ----
    hipMemsetAsync(cntR, 0, (size_t)N * 11 * 4, stream);
    k_count<<<(E + 255) / 256, 256, 0, stream>>>(ei, et, cntR, cntRT, cntCT, E);
    k_scales<<<(N + 255) / 256, 256, 0, stream>>>(cntRT, sc_r, N);
    {
        int n1 = N, nb1 = (n1 + 2047) / 2048;
        k_scan1<<<nb1, 256, 0, stream>>>(cntR, offR, bsums, n1);
        k_scan2<<<1, 256, 0, stream>>>(bsums, nb1);
        k_scan3<<<nb1, 256, 0, stream>>>(offR, bsums, n1);
        int n2 = N * 3, nb2 = (n2 + 2047) / 2048;
        k_scan1<<<nb2, 256, 0, stream>>>(cntCT, offC, bsums, n2);
        k_scan2<<<1, 256, 0, stream>>>(bsums, nb2);
        k_scan3<<<nb2, 256, 0, stream>>>(offC, bsums, n2);
    }
    k_scatter<<<(E + 255) / 256, 256, 0, stream>>>(ei, et, sc_r, offR, fillR, idxR,
                                                   coefR, offC, fillC, idxC, E);

    // ---- weight transposes (fp32 -> bf16 [256][K]) ----
    k_wt<<<dim3(8, 8), 256, 0, stream>>>(mlp_w1, w1t, 256);
    k_wt<<<dim3(8, 8), 256, 0, stream>>>(mlp_w2, w2t, 256);
    k_wt<<<dim3(24, 8), 256, 0, stream>>>(r1_wrel, r1relt, 768);
    k_wt<<<dim3(8, 8), 256, 0, stream>>>(r1_wroot, r1roott, 256);
    k_wt<<<dim3(24, 8), 256, 0, stream>>>(r2_wrel, r2relt, 768);
    k_wt<<<dim3(8, 8), 256, 0, stream>>>(r2_wroot, r2roott, 256);

    // ---- MLP branch ----
    {
        dim3 g((N + 127) / 128, 2);
        k_gemm_mfma<<<g, 256, 0, stream>>>(xb, 256, w1t, nullptr, 0, nullptr,
                                           mlp_b1, mbn1_g, mbn1_b, mbn1_m, mbn1_v,
                                           regA, N);
        k_gemm_mfma<<<g, 256, 0, stream>>>(regA, 256, w2t, nullptr, 0, nullptr,
                                           mlp_b2, mbn2_g, mbn2_b, mbn2_m, mbn2_v,
                                           regB, N);
    }

    // ---- SCRE: regA := bf16(h) ----
    k_scre_gather<<<(N + 7) / 8, 256, 0, stream>>>(xb, idxR, coefR, offR, cntR, regA, N);

    // ---- RGCN layer 1: regC = relu(bn(means(regA)@wrel + regA@wroot + b)) ----
    for (int ch = 0; ch < nch; ++ch) {
        int n0 = ch * Nc;
        int n1 = (n0 + Nc < N) ? n0 + Nc : N;
        int Mc = n1 - n0;
        int s0 = n0 * 3, s1 = n1 * 3;
        k_rgcn_gather<<<(s1 - s0 + 7) / 8, 256, 0, stream>>>(regA, idxC, offC, cntCT,
                                                             CH, s0, s1);
        dim3 g((Mc + 127) / 128, 2);
        k_gemm_mfma<<<g, 256, 0, stream>>>(CH, 768, r1relt,
                                           regA + (size_t)n0 * 256, 256, r1roott,
                                           r1_b, gbn1_g, gbn1_b, gbn1_m, gbn1_v,
                                           regC + (size_t)n0 * 256, Mc);
    }

    // ---- RGCN layer 2: regA = relu(bn(means(regC)@wrel + regC@wroot + b)) ----
    for (int ch = 0; ch < nch; ++ch) {
        int n0 = ch * Nc;
        int n1 = (n0 + Nc < N) ? n0 + Nc : N;
        int Mc = n1 - n0;
        int s0 = n0 * 3, s1 = n1 * 3;
        k_rgcn_gather<<<(s1 - s0 + 7) / 8, 256, 0, stream>>>(regC, idxC, offC, cntCT,
                                                             CH, s0, s1);
        dim3 g((Mc + 127) / 128, 2);
        k_gemm_mfma<<<g, 256, 0, stream>>>(CH, 768, r2relt,
                                           regC + (size_t)n0 * 256, 256, r2roott,
                                           r2_b, gbn2_g, gbn2_b, gbn2_m, gbn2_v,
                                           regA + (size_t)n0 * 256, Mc);
    }

    // ---- head ----
    k_head<<<(N + 3) / 4, 256, 0, stream>>>(regB, regA, out_w, out_b, (float*)d_out, N);
}